// Round 11
// baseline (845.189 us; speedup 1.0000x reference)
//
#include <hip/hip_runtime.h>
#include <hip/hip_bf16.h>

// LinearFLH: out[m,n] = sx[m]*sw[n]*(x[m,:].w[n,:]) + bias[n]
// M=8192, N=11008, K=4096. All harness buffers FLOAT32 (fp16 ref -> "else
// float" rule). Pipeline: (1) f32->bf16 convert of X,W into d_ws, (2) 256x256
// BK=64 bf16 MFMA GEMM, 8 waves, dbuf LDS with COUNTED vmcnt (T4):
//   barrier-A | STAGE(kt+1 -> buf^1) | vmcnt(8) | barrier-B | 24 ds_read + 64 MFMA
// Proof: per-wave vmcnt(8) completes everything older than the newest 8 loads
// (= tile kt); identical issue order on all waves + barrier-B => cross-wave RAW
// safe. Barrier-A orders all reads of buf^1 before its overwrite (WAR safe).
// Tile kt+1's DMA stays in flight across both barriers (~2500cy window).
// R10 (syncthreads drain) measured 5376 cy/tile vs 2509 cy MFMA floor.

#define M_DIM 8192
#define N_DIM 11008
#define K_DIM 4096
#define BM 256
#define BN 256
#define BK 64
#define NT (K_DIM / BK)                       // 64 K-tiles
#define NWG ((M_DIM / BM) * (N_DIM / BN))     // 32*43 = 1376, % 8 == 0

#define X_ELEMS (M_DIM * K_DIM)
#define W_ELEMS (N_DIM * K_DIM)
#define WS_NEEDED ((size_t)(X_ELEMS + W_ELEMS) * 2)

typedef __bf16 bf16x8 __attribute__((ext_vector_type(8)));
typedef float f32x4 __attribute__((ext_vector_type(4)));
typedef unsigned short u16x4 __attribute__((ext_vector_type(4)));
typedef unsigned short u16x8 __attribute__((ext_vector_type(8)));

typedef __attribute__((address_space(3))) void lds_void;
typedef const __attribute__((address_space(1))) void gmem_void;

// f32 -> bf16 bits, round-to-nearest-even (inputs finite)
__device__ __forceinline__ unsigned short f2bf(float f) {
    union { float f; unsigned int u; } c; c.f = f;
    unsigned int r = c.u + 0x7FFFu + ((c.u >> 16) & 1u);
    return (unsigned short)(r >> 16);
}

// ---------------- elementwise convert: f32 -> bf16 (proven R8) ----------------
__global__ __launch_bounds__(256) void convert_f32_to_bf16(
    const float* __restrict__ in, unsigned short* __restrict__ out, int n)
{
    int idx = (blockIdx.x * 256 + threadIdx.x) * 8;
    const int stride = gridDim.x * 256 * 8;
    for (; idx < n; idx += stride) {
        const f32x4 a = *(const f32x4*)(in + idx);
        const f32x4 b = *(const f32x4*)(in + idx + 4);
        u16x8 o;
        #pragma unroll
        for (int q = 0; q < 4; ++q) { o[q] = f2bf(a[q]); o[q + 4] = f2bf(b[q]); }
        *(u16x8*)(out + idx) = o;
    }
}

// ---------------- main GEMM: 256x256, 8 waves, counted-vmcnt dbuf ----------------
// LDS: buf c at c*32768 (ushort elems): A [256][64] at +0, B [256][64] at +16384.
// T2 swizzle (both sides, rule #21): lds[row][col] = global[row][col ^ ((row&7)<<3)].
__global__ __launch_bounds__(512, 2) void linear_flh_gemm_256(
    const unsigned short* __restrict__ Xb,   // [M,K] bf16 bits (ws)
    const unsigned short* __restrict__ Wb,   // [N,K] bf16 bits (ws)
    const float* __restrict__ SX,            // [M]
    const float* __restrict__ SW,            // [N]
    const float* __restrict__ BIAS,          // [N]
    float* __restrict__ OUT)                 // [M,N] f32
{
    __shared__ unsigned short lds[65536];    // 128 KiB -> 1 workgroup/CU

    const int t    = threadIdx.x;     // 0..511
    const int lane = t & 63;
    const int wid  = t >> 6;          // 0..7
    const int qr   = wid >> 2;        // 0..1: wave-row within 128x128 quadrant
    const int wcol = wid & 3;         // 0..3: wave-col within quadrant
    const int cl   = lane & 15;       // fragment row/col
    const int rl   = lane >> 4;       // 0..3: k-group

    // T1: XCD swizzle (1376 % 8 == 0 -> bijective)
    int bid = blockIdx.x;
    bid = (bid & 7) * (NWG / 8) + (bid >> 3);
    const int mBase = (bid / (N_DIM / BN)) * BM;
    const int nBase = (bid % (N_DIM / BN)) * BN;

    // T2 read-side: element col = (kk*32 + rl*8) ^ ((row&7)<<3); row&7 == cl&7
    // for every fragment row below -> per-thread constants.
    const int colK0 = (rl * 8) ^ ((cl & 7) << 3);
    const int colK1 = colK0 ^ 32;

    f32x4 acc[4][4][2];   // [quadrant][mi][ni] -- all indices compile-time
    #pragma unroll
    for (int q = 0; q < 4; ++q)
        #pragma unroll
        for (int mi = 0; mi < 4; ++mi)
            #pragma unroll
            for (int ni = 0; ni < 2; ++ni)
                acc[q][mi][ni] = (f32x4){0.f, 0.f, 0.f, 0.f};

    // Stage one K-tile (A+B) into buf DST_ from k-column KCOL_: 8 DMA/thread.
    // LDS dest linear (DMA rule, m104); global source col pre-swizzled with
    // the read-side involution (rule #21 both-sides).
    #define STAGE_TILE(DST_, KCOL_)                                            \
        { _Pragma("unroll")                                                    \
          for (int it_ = 0; it_ < 4; ++it_) {                                  \
              const int e_ = it_ * 4096 + t * 8;                               \
              const int r_ = e_ >> 6;                                          \
              const int c_ = ((t & 7) * 8) ^ ((r_ & 7) << 3);                  \
              __builtin_amdgcn_global_load_lds(                                \
                  (gmem_void*)(Xb + (size_t)(mBase + r_) * K_DIM + (KCOL_) + c_),\
                  (lds_void*)(lds + (DST_) + e_), 16, 0, 0);                   \
              __builtin_amdgcn_global_load_lds(                                \
                  (gmem_void*)(Wb + (size_t)(nBase + r_) * K_DIM + (KCOL_) + c_),\
                  (lds_void*)(lds + (DST_) + 16384 + e_), 16, 0, 0);           \
          } }

    STAGE_TILE(0, 0);   // prologue: tile 0 -> buf 0 (8 loads in flight)

    for (int kt = 0; kt < NT; ++kt) {
        const int cur = kt & 1;

        // barrier-A: every wave finished reading buf cur^1 (tile kt-1) -> safe
        // to overwrite. Raw s_barrier: does NOT drain vmcnt (that's the point).
        __builtin_amdgcn_s_barrier();
        __builtin_amdgcn_sched_barrier(0);

        if (kt + 1 < NT) {
            STAGE_TILE((cur ^ 1) * 32768, (kt + 1) * BK);
            // per-wave queue: [tile kt (8, maybe in flight), tile kt+1 (8)].
            // vmcnt(8): oldest beyond the newest 8 complete => tile kt landed;
            // tile kt+1 stays in flight across barrier-B.
            asm volatile("s_waitcnt vmcnt(8)" ::: "memory");
        } else {
            asm volatile("s_waitcnt vmcnt(0)" ::: "memory");   // final tile drain
        }

        // barrier-B: all waves' vmcnt passed -> tile kt visible block-wide.
        __builtin_amdgcn_s_barrier();
        __builtin_amdgcn_sched_barrier(0);
        asm volatile("" ::: "memory");   // IR-level fence: no ds_read hoisting

        const int abase = cur * 32768;
        const int bbase = abase + 16384;

        // Hoisted fragment reads: 24 ds_read_b128/wave (was 48 via per-quadrant
        // re-reads) -> LDS traffic 192 KB/CU/tile ~ 2260cy < MFMA 2509cy.
        bf16x8 af[2][4][2], bf[2][2][2];
        #pragma unroll
        for (int mh = 0; mh < 2; ++mh)
            #pragma unroll
            for (int mi = 0; mi < 4; ++mi) {
                const int row = mh * 128 + qr * 64 + mi * 16 + cl;
                af[mh][mi][0] = *(const bf16x8*)(lds + abase + row * 64 + colK0);
                af[mh][mi][1] = *(const bf16x8*)(lds + abase + row * 64 + colK1);
            }
        #pragma unroll
        for (int nh = 0; nh < 2; ++nh)
            #pragma unroll
            for (int ni = 0; ni < 2; ++ni) {
                const int row = nh * 128 + wcol * 32 + ni * 16 + cl;
                bf[nh][ni][0] = *(const bf16x8*)(lds + bbase + row * 64 + colK0);
                bf[nh][ni][1] = *(const bf16x8*)(lds + bbase + row * 64 + colK1);
            }

        __builtin_amdgcn_s_setprio(1);
        #pragma unroll
        for (int q = 0; q < 4; ++q) {
            const int mh = q >> 1, nh = q & 1;
            #pragma unroll
            for (int mi = 0; mi < 4; ++mi)
                #pragma unroll
                for (int ni = 0; ni < 2; ++ni) {
                    acc[q][mi][ni] = __builtin_amdgcn_mfma_f32_16x16x32_bf16(
                        af[mh][mi][0], bf[nh][ni][0], acc[q][mi][ni], 0, 0, 0);
                    acc[q][mi][ni] = __builtin_amdgcn_mfma_f32_16x16x32_bf16(
                        af[mh][mi][1], bf[nh][ni][1], acc[q][mi][ni], 0, 0, 0);
                }
        }
        __builtin_amdgcn_s_setprio(0);
    }
    #undef STAGE_TILE

    // Epilogue: out = acc * sx[row] * sw[col] + bias[col]; NT stores keep the
    // 360 MB f32 output from evicting bf16 operands out of L3.
    // C/D layout: col = lane&15, row = rl*4 + reg (m89/m91).
    #pragma unroll
    for (int q = 0; q < 4; ++q) {
        const int mh = q >> 1, nh = q & 1;
        #pragma unroll
        for (int mi = 0; mi < 4; ++mi) {
            const int rowb = mBase + mh * 128 + qr * 64 + mi * 16 + rl * 4;
            #pragma unroll
            for (int ni = 0; ni < 2; ++ni) {
                const int col = nBase + nh * 128 + wcol * 32 + ni * 16 + cl;
                const float swv = SW[col];
                const float bv  = BIAS[col];
                #pragma unroll
                for (int rr = 0; rr < 4; ++rr) {
                    const int row = rowb + rr;
                    float v = acc[q][mi][ni][rr] * SX[row] * swv + bv;
                    v = fminf(fmaxf(v, -1.0e5f), 1.0e5f);   // diagnostic sentinel
                    __builtin_nontemporal_store(v, OUT + (size_t)row * N_DIM + col);
                }
            }
        }
    }
}

// ---------------- fallback (R7/R8-proven): inline-convert reg-staged 128^2 ----------------
#define FBM 128
#define FBK 64
__global__ __launch_bounds__(256) void linear_flh_gemm_f32in(
    const float* __restrict__ X, const float* __restrict__ SX,
    const float* __restrict__ W, const float* __restrict__ SW,
    const float* __restrict__ BIAS, float* __restrict__ OUT)
{
    __shared__ alignas(16) unsigned short smA[FBM * FBK];
    __shared__ alignas(16) unsigned short smB[FBM * FBK];
    const int t = threadIdx.x;
    const int lane = t & 63, wave = t >> 6;
    const int wr = wave >> 1, wc = wave & 1;
    int bid = blockIdx.x;
    bid = (bid & 7) * ((M_DIM / FBM) * (N_DIM / FBM) / 8) + (bid >> 3);
    const int mBase = (bid / (N_DIM / FBM)) * FBM;
    const int nBase = (bid % (N_DIM / FBM)) * FBM;
    const int cl = lane & 15, rl = lane >> 4;
    f32x4 acc[4][4];
    #pragma unroll
    for (int i = 0; i < 4; ++i)
        #pragma unroll
        for (int j = 0; j < 4; ++j) acc[i][j] = (f32x4){0.f, 0.f, 0.f, 0.f};
    for (int kt = 0; kt < K_DIM / FBK; ++kt) {
        const int kBase = kt * FBK;
        f32x4 ra[8], rb[8];
        #pragma unroll
        for (int cc = 0; cc < 8; ++cc) {
            const int e = cc * 1024 + t * 4;
            const int r = e >> 6, c = e & 63;
            ra[cc] = *(const f32x4*)(X + (size_t)(mBase + r) * K_DIM + kBase + c);
            rb[cc] = *(const f32x4*)(W + (size_t)(nBase + r) * K_DIM + kBase + c);
        }
        __syncthreads();
        #pragma unroll
        for (int cc = 0; cc < 8; ++cc) {
            const int e = cc * 1024 + t * 4;
            u16x4 pa, pb;
            #pragma unroll
            for (int q = 0; q < 4; ++q) { pa[q] = f2bf(ra[cc][q]); pb[q] = f2bf(rb[cc][q]); }
            *(u16x4*)(smA + e) = pa;
            *(u16x4*)(smB + e) = pb;
        }
        __syncthreads();
        #pragma unroll
        for (int kk = 0; kk < FBK / 32; ++kk) {
            bf16x8 afr[4], bfr[4];
            #pragma unroll
            for (int i = 0; i < 4; ++i) {
                afr[i] = *(const bf16x8*)(smA + (wr * 64 + i * 16 + cl) * FBK + kk * 32 + rl * 8);
                bfr[i] = *(const bf16x8*)(smB + (wc * 64 + i * 16 + cl) * FBK + kk * 32 + rl * 8);
            }
            #pragma unroll
            for (int i = 0; i < 4; ++i)
                #pragma unroll
                for (int j = 0; j < 4; ++j)
                    acc[i][j] = __builtin_amdgcn_mfma_f32_16x16x32_bf16(
                        afr[i], bfr[j], acc[i][j], 0, 0, 0);
        }
    }
    #pragma unroll
    for (int j = 0; j < 4; ++j) {
        const int gn = nBase + wc * 64 + j * 16 + cl;
        const float swv = SW[gn], bv = BIAS[gn];
        #pragma unroll
        for (int i = 0; i < 4; ++i) {
            const int gmb = mBase + wr * 64 + i * 16 + rl * 4;
            #pragma unroll
            for (int r = 0; r < 4; ++r) {
                float v = acc[i][j][r] * SX[gmb + r] * swv + bv;
                v = fminf(fmaxf(v, -1.0e5f), 1.0e5f);
                OUT[(size_t)(gmb + r) * N_DIM + gn] = v;
            }
        }
    }
}

extern "C" void kernel_launch(void* const* d_in, const int* in_sizes, int n_in,
                              void* d_out, int out_size, void* d_ws, size_t ws_size,
                              hipStream_t stream) {
    const void* pX = d_in[0]; const void* pSX = d_in[1]; const void* pW = d_in[2];
    const void* pSW = d_in[3]; const void* pBS = d_in[4];
    for (int i = 0; i < n_in; ++i) {
        if (in_sizes[i] == M_DIM * K_DIM)      pX  = d_in[i];
        else if (in_sizes[i] == M_DIM)         pSX = d_in[i];
        else if (in_sizes[i] == N_DIM * K_DIM) pW  = d_in[i];
    }
    {
        int first = -1, second = -1;
        for (int i = 0; i < n_in; ++i)
            if (in_sizes[i] == N_DIM) { if (first < 0) first = i; else if (second < 0) second = i; }
        if (first >= 0)  pSW = d_in[first];
        if (second >= 0) pBS = d_in[second];
    }

    if (ws_size >= WS_NEEDED) {
        unsigned short* Xb = (unsigned short*)d_ws;
        unsigned short* Wb = Xb + X_ELEMS;
        convert_f32_to_bf16<<<2048, 256, 0, stream>>>((const float*)pX, Xb, X_ELEMS);
        convert_f32_to_bf16<<<2048, 256, 0, stream>>>((const float*)pW, Wb, W_ELEMS);
        linear_flh_gemm_256<<<dim3(NWG), 512, 0, stream>>>(
            Xb, Wb, (const float*)pSX, (const float*)pSW, (const float*)pBS,
            (float*)d_out);
    } else {
        dim3 grid((M_DIM / FBM) * (N_DIM / FBM));
        linear_flh_gemm_f32in<<<grid, 256, 0, stream>>>(
            (const float*)pX, (const float*)pSX, (const float*)pW,
            (const float*)pSW, (const float*)pBS, (float*)d_out);
    }
}

// Round 12
// 756.521 us; speedup vs baseline: 1.1172x; 1.1172x over previous
//
#include <hip/hip_runtime.h>
#include <hip/hip_bf16.h>

// LinearFLH: out[m,n] = sx[m]*sw[n]*(x[m,:].w[n,:]) + bias[n]
// M=8192, N=11008, K=4096. All harness buffers FLOAT32 (fp16 ref -> "else
// float" rule). Pipeline: (1) f32->bf16 convert of X,W into d_ws, (2) 256x256
// BK=64 bf16 MFMA GEMM, 8 waves, dbuf LDS, ONE __syncthreads per K-tile (R10
// base, deterministic 779us) + MINIMAL-READ FRAGMENT HOIST: 24 ds_read_b128
// per wave per K-tile (was 48 per-quadrant) issued in one block, NO fences --
// compiler's fine-grained lgkmcnt overlaps reads with MFMA (m97-verified).
// R11 lesson: sched_barrier(0)/asm-vmcnt pinning regressed (m141 class).

#define M_DIM 8192
#define N_DIM 11008
#define K_DIM 4096
#define BM 256
#define BN 256
#define BK 64
#define NT (K_DIM / BK)                       // 64 K-tiles
#define NWG ((M_DIM / BM) * (N_DIM / BN))     // 32*43 = 1376, % 8 == 0

#define X_ELEMS (M_DIM * K_DIM)
#define W_ELEMS (N_DIM * K_DIM)
#define WS_NEEDED ((size_t)(X_ELEMS + W_ELEMS) * 2)

typedef __bf16 bf16x8 __attribute__((ext_vector_type(8)));
typedef float f32x4 __attribute__((ext_vector_type(4)));
typedef unsigned short u16x4 __attribute__((ext_vector_type(4)));
typedef unsigned short u16x8 __attribute__((ext_vector_type(8)));

typedef __attribute__((address_space(3))) void lds_void;
typedef const __attribute__((address_space(1))) void gmem_void;

// f32 -> bf16 bits, round-to-nearest-even (inputs finite)
__device__ __forceinline__ unsigned short f2bf(float f) {
    union { float f; unsigned int u; } c; c.f = f;
    unsigned int r = c.u + 0x7FFFu + ((c.u >> 16) & 1u);
    return (unsigned short)(r >> 16);
}

// ---------------- elementwise convert: f32 -> bf16 (proven R8) ----------------
__global__ __launch_bounds__(256) void convert_f32_to_bf16(
    const float* __restrict__ in, unsigned short* __restrict__ out, int n)
{
    int idx = (blockIdx.x * 256 + threadIdx.x) * 8;
    const int stride = gridDim.x * 256 * 8;
    for (; idx < n; idx += stride) {
        const f32x4 a = *(const f32x4*)(in + idx);
        const f32x4 b = *(const f32x4*)(in + idx + 4);
        u16x8 o;
        #pragma unroll
        for (int q = 0; q < 4; ++q) { o[q] = f2bf(a[q]); o[q + 4] = f2bf(b[q]); }
        *(u16x8*)(out + idx) = o;
    }
}

// ---------------- main GEMM: 256x256, 8 waves, dbuf + 1 barrier/K-tile ----------------
// LDS: buf c at c*32768 (ushort elems): A [256][64] at +0, B [256][64] at +16384.
// T2 swizzle (both sides, rule #21): lds[row][col] = global[row][col ^ ((row&7)<<3)].
__global__ __launch_bounds__(512, 2) void linear_flh_gemm_256(
    const unsigned short* __restrict__ Xb,   // [M,K] bf16 bits (ws)
    const unsigned short* __restrict__ Wb,   // [N,K] bf16 bits (ws)
    const float* __restrict__ SX,            // [M]
    const float* __restrict__ SW,            // [N]
    const float* __restrict__ BIAS,          // [N]
    float* __restrict__ OUT)                 // [M,N] f32
{
    __shared__ unsigned short lds[65536];    // 128 KiB -> 1 workgroup/CU

    const int t    = threadIdx.x;     // 0..511
    const int lane = t & 63;
    const int wid  = t >> 6;          // 0..7
    const int qr   = wid >> 2;        // 0..1: wave-row within 128x128 quadrant
    const int wcol = wid & 3;         // 0..3: wave-col within quadrant
    const int cl   = lane & 15;       // fragment row/col
    const int rl   = lane >> 4;       // 0..3: k-group

    // T1: XCD swizzle (1376 % 8 == 0 -> bijective)
    int bid = blockIdx.x;
    bid = (bid & 7) * (NWG / 8) + (bid >> 3);
    const int mBase = (bid / (N_DIM / BN)) * BM;
    const int nBase = (bid % (N_DIM / BN)) * BN;

    // T2 read-side: element col = (kk*32 + rl*8) ^ ((row&7)<<3); row&7 == cl&7
    // for every fragment row below -> per-thread constants.
    const int colK0 = (rl * 8) ^ ((cl & 7) << 3);
    const int colK1 = colK0 ^ 32;

    f32x4 acc[4][4][2];   // [quadrant mh*2+nh][mi][ni] -- compile-time indices
    #pragma unroll
    for (int q = 0; q < 4; ++q)
        #pragma unroll
        for (int mi = 0; mi < 4; ++mi)
            #pragma unroll
            for (int ni = 0; ni < 2; ++ni)
                acc[q][mi][ni] = (f32x4){0.f, 0.f, 0.f, 0.f};

    // Stage one K-tile (A+B) into buf DST_ from k-column KCOL_: 8 DMA/thread.
    // LDS dest linear (DMA rule, m104); global source col pre-swizzled with
    // the read-side involution (rule #21 both-sides).
    #define STAGE_TILE(DST_, KCOL_)                                            \
        { _Pragma("unroll")                                                    \
          for (int it_ = 0; it_ < 4; ++it_) {                                  \
              const int e_ = it_ * 4096 + t * 8;                               \
              const int r_ = e_ >> 6;                                          \
              const int c_ = ((t & 7) * 8) ^ ((r_ & 7) << 3);                  \
              __builtin_amdgcn_global_load_lds(                                \
                  (gmem_void*)(Xb + (size_t)(mBase + r_) * K_DIM + (KCOL_) + c_),\
                  (lds_void*)(lds + (DST_) + e_), 16, 0, 0);                   \
              __builtin_amdgcn_global_load_lds(                                \
                  (gmem_void*)(Wb + (size_t)(nBase + r_) * K_DIM + (KCOL_) + c_),\
                  (lds_void*)(lds + (DST_) + 16384 + e_), 16, 0, 0);           \
          } }

    STAGE_TILE(0, 0);   // prologue: tile 0 -> buf 0

    for (int kt = 0; kt < NT; ++kt) {
        const int cur = kt & 1;
        // __syncthreads: drains vmcnt -> buf[cur] (staged last iter by all
        // waves) is landed & visible; orders last iter's reads of buf[cur^1]
        // before its overwrite below. Single barrier per K-tile (R10-proven).
        __syncthreads();
        if (kt + 1 < NT) STAGE_TILE((cur ^ 1) * 32768, (kt + 1) * BK);

        const int abase = cur * 32768;
        const int bbase = abase + 16384;

        // Minimal fragment set: 24 ds_read_b128 (16 A + 8 B), issued as one
        // block with NO fences; compiler lgkmcnt lets q00 MFMAs start while
        // a1/b1 reads are still in flight.
        bf16x8 a0[4][2], a1[4][2], b0[2][2], b1[2][2];
        #pragma unroll
        for (int mi = 0; mi < 4; ++mi) {
            const int row = qr * 64 + mi * 16 + cl;                 // A half0
            a0[mi][0] = *(const bf16x8*)(lds + abase + row * 64 + colK0);
            a0[mi][1] = *(const bf16x8*)(lds + abase + row * 64 + colK1);
        }
        #pragma unroll
        for (int ni = 0; ni < 2; ++ni) {
            const int row = wcol * 32 + ni * 16 + cl;               // B half0
            b0[ni][0] = *(const bf16x8*)(lds + bbase + row * 64 + colK0);
            b0[ni][1] = *(const bf16x8*)(lds + bbase + row * 64 + colK1);
        }
        #pragma unroll
        for (int ni = 0; ni < 2; ++ni) {
            const int row = 128 + wcol * 32 + ni * 16 + cl;         // B half1
            b1[ni][0] = *(const bf16x8*)(lds + bbase + row * 64 + colK0);
            b1[ni][1] = *(const bf16x8*)(lds + bbase + row * 64 + colK1);
        }
        #pragma unroll
        for (int mi = 0; mi < 4; ++mi) {
            const int row = 128 + qr * 64 + mi * 16 + cl;           // A half1
            a1[mi][0] = *(const bf16x8*)(lds + abase + row * 64 + colK0);
            a1[mi][1] = *(const bf16x8*)(lds + abase + row * 64 + colK1);
        }

        // MFMA order q00 -> q01 -> q11 -> q10 (each operand pair reused
        // back-to-back; q00 depends only on the first 12 reads).
        __builtin_amdgcn_s_setprio(1);
        #pragma unroll
        for (int mi = 0; mi < 4; ++mi)
            #pragma unroll
            for (int ni = 0; ni < 2; ++ni) {            // q00: a0 x b0
                acc[0][mi][ni] = __builtin_amdgcn_mfma_f32_16x16x32_bf16(
                    a0[mi][0], b0[ni][0], acc[0][mi][ni], 0, 0, 0);
                acc[0][mi][ni] = __builtin_amdgcn_mfma_f32_16x16x32_bf16(
                    a0[mi][1], b0[ni][1], acc[0][mi][ni], 0, 0, 0);
            }
        #pragma unroll
        for (int mi = 0; mi < 4; ++mi)
            #pragma unroll
            for (int ni = 0; ni < 2; ++ni) {            // q01: a0 x b1
                acc[1][mi][ni] = __builtin_amdgcn_mfma_f32_16x16x32_bf16(
                    a0[mi][0], b1[ni][0], acc[1][mi][ni], 0, 0, 0);
                acc[1][mi][ni] = __builtin_amdgcn_mfma_f32_16x16x32_bf16(
                    a0[mi][1], b1[ni][1], acc[1][mi][ni], 0, 0, 0);
            }
        #pragma unroll
        for (int mi = 0; mi < 4; ++mi)
            #pragma unroll
            for (int ni = 0; ni < 2; ++ni) {            // q11: a1 x b1
                acc[3][mi][ni] = __builtin_amdgcn_mfma_f32_16x16x32_bf16(
                    a1[mi][0], b1[ni][0], acc[3][mi][ni], 0, 0, 0);
                acc[3][mi][ni] = __builtin_amdgcn_mfma_f32_16x16x32_bf16(
                    a1[mi][1], b1[ni][1], acc[3][mi][ni], 0, 0, 0);
            }
        #pragma unroll
        for (int mi = 0; mi < 4; ++mi)
            #pragma unroll
            for (int ni = 0; ni < 2; ++ni) {            // q10: a1 x b0
                acc[2][mi][ni] = __builtin_amdgcn_mfma_f32_16x16x32_bf16(
                    a1[mi][0], b0[ni][0], acc[2][mi][ni], 0, 0, 0);
                acc[2][mi][ni] = __builtin_amdgcn_mfma_f32_16x16x32_bf16(
                    a1[mi][1], b0[ni][1], acc[2][mi][ni], 0, 0, 0);
            }
        __builtin_amdgcn_s_setprio(0);
    }
    #undef STAGE_TILE

    // Epilogue: out = acc * sx[row] * sw[col] + bias[col]; NT stores keep the
    // 360 MB f32 output from evicting bf16 operands out of L3.
    // C/D layout: col = lane&15, row = rl*4 + reg (m89/m91).
    #pragma unroll
    for (int q = 0; q < 4; ++q) {
        const int mh = q >> 1, nh = q & 1;
        #pragma unroll
        for (int mi = 0; mi < 4; ++mi) {
            const int rowb = mBase + mh * 128 + qr * 64 + mi * 16 + rl * 4;
            #pragma unroll
            for (int ni = 0; ni < 2; ++ni) {
                const int col = nBase + nh * 128 + wcol * 32 + ni * 16 + cl;
                const float swv = SW[col];
                const float bv  = BIAS[col];
                #pragma unroll
                for (int rr = 0; rr < 4; ++rr) {
                    const int row = rowb + rr;
                    float v = acc[q][mi][ni][rr] * SX[row] * swv + bv;
                    v = fminf(fmaxf(v, -1.0e5f), 1.0e5f);   // diagnostic sentinel
                    __builtin_nontemporal_store(v, OUT + (size_t)row * N_DIM + col);
                }
            }
        }
    }
}

// ---------------- fallback (R7/R8-proven): inline-convert reg-staged 128^2 ----------------
#define FBM 128
#define FBK 64
__global__ __launch_bounds__(256) void linear_flh_gemm_f32in(
    const float* __restrict__ X, const float* __restrict__ SX,
    const float* __restrict__ W, const float* __restrict__ SW,
    const float* __restrict__ BIAS, float* __restrict__ OUT)
{
    __shared__ alignas(16) unsigned short smA[FBM * FBK];
    __shared__ alignas(16) unsigned short smB[FBM * FBK];
    const int t = threadIdx.x;
    const int lane = t & 63, wave = t >> 6;
    const int wr = wave >> 1, wc = wave & 1;
    int bid = blockIdx.x;
    bid = (bid & 7) * ((M_DIM / FBM) * (N_DIM / FBM) / 8) + (bid >> 3);
    const int mBase = (bid / (N_DIM / FBM)) * FBM;
    const int nBase = (bid % (N_DIM / FBM)) * FBM;
    const int cl = lane & 15, rl = lane >> 4;
    f32x4 acc[4][4];
    #pragma unroll
    for (int i = 0; i < 4; ++i)
        #pragma unroll
        for (int j = 0; j < 4; ++j) acc[i][j] = (f32x4){0.f, 0.f, 0.f, 0.f};
    for (int kt = 0; kt < K_DIM / FBK; ++kt) {
        const int kBase = kt * FBK;
        f32x4 ra[8], rb[8];
        #pragma unroll
        for (int cc = 0; cc < 8; ++cc) {
            const int e = cc * 1024 + t * 4;
            const int r = e >> 6, c = e & 63;
            ra[cc] = *(const f32x4*)(X + (size_t)(mBase + r) * K_DIM + kBase + c);
            rb[cc] = *(const f32x4*)(W + (size_t)(nBase + r) * K_DIM + kBase + c);
        }
        __syncthreads();
        #pragma unroll
        for (int cc = 0; cc < 8; ++cc) {
            const int e = cc * 1024 + t * 4;
            u16x4 pa, pb;
            #pragma unroll
            for (int q = 0; q < 4; ++q) { pa[q] = f2bf(ra[cc][q]); pb[q] = f2bf(rb[cc][q]); }
            *(u16x4*)(smA + e) = pa;
            *(u16x4*)(smB + e) = pb;
        }
        __syncthreads();
        #pragma unroll
        for (int kk = 0; kk < FBK / 32; ++kk) {
            bf16x8 afr[4], bfr[4];
            #pragma unroll
            for (int i = 0; i < 4; ++i) {
                afr[i] = *(const bf16x8*)(smA + (wr * 64 + i * 16 + cl) * FBK + kk * 32 + rl * 8);
                bfr[i] = *(const bf16x8*)(smB + (wc * 64 + i * 16 + cl) * FBK + kk * 32 + rl * 8);
            }
            #pragma unroll
            for (int i = 0; i < 4; ++i)
                #pragma unroll
                for (int j = 0; j < 4; ++j)
                    acc[i][j] = __builtin_amdgcn_mfma_f32_16x16x32_bf16(
                        afr[i], bfr[j], acc[i][j], 0, 0, 0);
        }
    }
    #pragma unroll
    for (int j = 0; j < 4; ++j) {
        const int gn = nBase + wc * 64 + j * 16 + cl;
        const float swv = SW[gn], bv = BIAS[gn];
        #pragma unroll
        for (int i = 0; i < 4; ++i) {
            const int gmb = mBase + wr * 64 + i * 16 + rl * 4;
            #pragma unroll
            for (int r = 0; r < 4; ++r) {
                float v = acc[i][j][r] * SX[gmb + r] * swv + bv;
                v = fminf(fmaxf(v, -1.0e5f), 1.0e5f);
                OUT[(size_t)(gmb + r) * N_DIM + gn] = v;
            }
        }
    }
}

extern "C" void kernel_launch(void* const* d_in, const int* in_sizes, int n_in,
                              void* d_out, int out_size, void* d_ws, size_t ws_size,
                              hipStream_t stream) {
    const void* pX = d_in[0]; const void* pSX = d_in[1]; const void* pW = d_in[2];
    const void* pSW = d_in[3]; const void* pBS = d_in[4];
    for (int i = 0; i < n_in; ++i) {
        if (in_sizes[i] == M_DIM * K_DIM)      pX  = d_in[i];
        else if (in_sizes[i] == M_DIM)         pSX = d_in[i];
        else if (in_sizes[i] == N_DIM * K_DIM) pW  = d_in[i];
    }
    {
        int first = -1, second = -1;
        for (int i = 0; i < n_in; ++i)
            if (in_sizes[i] == N_DIM) { if (first < 0) first = i; else if (second < 0) second = i; }
        if (first >= 0)  pSW = d_in[first];
        if (second >= 0) pBS = d_in[second];
    }

    if (ws_size >= WS_NEEDED) {
        unsigned short* Xb = (unsigned short*)d_ws;
        unsigned short* Wb = Xb + X_ELEMS;
        convert_f32_to_bf16<<<2048, 256, 0, stream>>>((const float*)pX, Xb, X_ELEMS);
        convert_f32_to_bf16<<<2048, 256, 0, stream>>>((const float*)pW, Wb, W_ELEMS);
        linear_flh_gemm_256<<<dim3(NWG), 512, 0, stream>>>(
            Xb, Wb, (const float*)pSX, (const float*)pSW, (const float*)pBS,
            (float*)d_out);
    } else {
        dim3 grid((M_DIM / FBM) * (N_DIM / FBM));
        linear_flh_gemm_f32in<<<grid, 256, 0, stream>>>(
            (const float*)pX, (const float*)pSX, (const float*)pW,
            (const float*)pSW, (const float*)pBS, (float*)d_out);
    }
}

// Round 13
// 731.832 us; speedup vs baseline: 1.1549x; 1.0337x over previous
//
#include <hip/hip_runtime.h>
#include <hip/hip_bf16.h>

// LinearFLH: out[m,n] = sx[m]*sw[n]*(x[m,:].w[n,:]) + bias[n]
// M=8192, N=11008, K=4096. All harness buffers FLOAT32 (fp16 ref -> "else
// float" rule). Pipeline: (1) f32->bf16 convert of X,W into d_ws, (2) 256x256
// BK=64 bf16 MFMA GEMM, 8 waves, dbuf LDS, 4-PHASE COUNTED-VMCNT schedule
// (T3+T4): per tile, phases {vmcnt(4); s_barrier; fence; stage 1 group;
// minimal ds_reads; 16 MFMA} in quadrant order q00,q01,q11,q10; stage order
// [A0',B0',B1',A1']; ph3 needs no wait/barrier. Tail iter peeled with counts
// (4,2,0) -- this was R9's race (steady counts under-wait once staging stops).
// R12 baseline: 756us, MfmaUtil 48.7%, syncthreads drain = critical path.

#define M_DIM 8192
#define N_DIM 11008
#define K_DIM 4096
#define BM 256
#define BN 256
#define BK 64
#define NT (K_DIM / BK)                       // 64 K-tiles
#define NWG ((M_DIM / BM) * (N_DIM / BN))     // 32*43 = 1376, % 8 == 0

#define X_ELEMS (M_DIM * K_DIM)
#define W_ELEMS (N_DIM * K_DIM)
#define WS_NEEDED ((size_t)(X_ELEMS + W_ELEMS) * 2)

typedef __bf16 bf16x8 __attribute__((ext_vector_type(8)));
typedef float f32x4 __attribute__((ext_vector_type(4)));
typedef unsigned short u16x4 __attribute__((ext_vector_type(4)));
typedef unsigned short u16x8 __attribute__((ext_vector_type(8)));

typedef __attribute__((address_space(3))) void lds_void;
typedef const __attribute__((address_space(1))) void gmem_void;

// f32 -> bf16 bits, round-to-nearest-even (inputs finite)
__device__ __forceinline__ unsigned short f2bf(float f) {
    union { float f; unsigned int u; } c; c.f = f;
    unsigned int r = c.u + 0x7FFFu + ((c.u >> 16) & 1u);
    return (unsigned short)(r >> 16);
}

// ---------------- elementwise convert: f32 -> bf16 (proven R8) ----------------
__global__ __launch_bounds__(256) void convert_f32_to_bf16(
    const float* __restrict__ in, unsigned short* __restrict__ out, int n)
{
    int idx = (blockIdx.x * 256 + threadIdx.x) * 8;
    const int stride = gridDim.x * 256 * 8;
    for (; idx < n; idx += stride) {
        const f32x4 a = *(const f32x4*)(in + idx);
        const f32x4 b = *(const f32x4*)(in + idx + 4);
        u16x8 o;
        #pragma unroll
        for (int q = 0; q < 4; ++q) { o[q] = f2bf(a[q]); o[q + 4] = f2bf(b[q]); }
        *(u16x8*)(out + idx) = o;
    }
}

// ---------------- main GEMM: 256x256, 8 waves, 4-phase counted-vmcnt ----------------
// LDS: buf c at c*32768 (ushort): A [256][64] at +0 (half h at +h*8192),
// B [256][64] at +16384 (half h at +16384+h*8192).
// T2 swizzle (both sides, rule #21): lds[row][col] = global[row][col ^ ((row&7)<<3)].
__global__ __launch_bounds__(512, 2) void linear_flh_gemm_256(
    const unsigned short* __restrict__ Xb,   // [M,K] bf16 bits (ws)
    const unsigned short* __restrict__ Wb,   // [N,K] bf16 bits (ws)
    const float* __restrict__ SX,            // [M]
    const float* __restrict__ SW,            // [N]
    const float* __restrict__ BIAS,          // [N]
    float* __restrict__ OUT)                 // [M,N] f32
{
    __shared__ unsigned short lds[65536];    // 128 KiB -> 1 workgroup/CU

    const int t    = threadIdx.x;     // 0..511
    const int lane = t & 63;
    const int wid  = t >> 6;          // 0..7
    const int qr   = wid >> 2;        // 0..1: wave-row within 128x128 quadrant
    const int wcol = wid & 3;         // 0..3: wave-col within quadrant
    const int cl   = lane & 15;       // fragment row/col
    const int rl   = lane >> 4;       // 0..3: k-group

    // T1: XCD swizzle (1376 % 8 == 0 -> bijective)
    int bid = blockIdx.x;
    bid = (bid & 7) * (NWG / 8) + (bid >> 3);
    const int mBase = (bid / (N_DIM / BN)) * BM;
    const int nBase = (bid % (N_DIM / BN)) * BN;

    // T2 read-side: element col = (k0) ^ ((row&7)<<3); row&7 == cl&7 below.
    const int colK0 = (rl * 8) ^ ((cl & 7) << 3);
    const int colK1 = colK0 ^ 32;

    f32x4 acc[4][4][2];   // [quadrant mh*2+nh][mi][ni]
    #pragma unroll
    for (int q = 0; q < 4; ++q)
        #pragma unroll
        for (int mi = 0; mi < 4; ++mi)
            #pragma unroll
            for (int ni = 0; ni < 2; ++ni)
                acc[q][mi][ni] = (f32x4){0.f, 0.f, 0.f, 0.f};

    // Stage one 128-row HALF (A or B) = 8192 elems = 2 gload_lds(16B)/thread.
    // LDS dest linear (m104); global col pre-swizzled (rule #21).
    #define STAGE_HALF(P_, ROWB_, DSTB_, KCOL_)                                \
        { _Pragma("unroll")                                                    \
          for (int q_ = 0; q_ < 2; ++q_) {                                     \
              const int e_ = q_ * 4096 + t * 8;                                \
              const int r_ = e_ >> 6;                                          \
              const int c_ = ((t & 7) * 8) ^ ((r_ & 7) << 3);                  \
              __builtin_amdgcn_global_load_lds(                                \
                  (gmem_void*)((P_) + (size_t)((ROWB_) + r_) * K_DIM + (KCOL_) + c_),\
                  (lds_void*)(lds + (DSTB_) + e_), 16, 0, 0);                  \
          } }

    #define READ_A(DST_, HB_)                                                  \
        { _Pragma("unroll")                                                    \
          for (int mi_ = 0; mi_ < 4; ++mi_) {                                  \
              const int row_ = qr * 64 + mi_ * 16 + cl;                        \
              DST_[mi_][0] = *(const bf16x8*)(lds + (HB_) + row_ * 64 + colK0);\
              DST_[mi_][1] = *(const bf16x8*)(lds + (HB_) + row_ * 64 + colK1);\
          } }
    #define READ_B(DST_, HB_)                                                  \
        { _Pragma("unroll")                                                    \
          for (int ni_ = 0; ni_ < 2; ++ni_) {                                  \
              const int row_ = wcol * 32 + ni_ * 16 + cl;                      \
              DST_[ni_][0] = *(const bf16x8*)(lds + (HB_) + row_ * 64 + colK0);\
              DST_[ni_][1] = *(const bf16x8*)(lds + (HB_) + row_ * 64 + colK1);\
          } }

    #define MFMA_Q(Q_, AF_, BF_)                                               \
        { __builtin_amdgcn_s_setprio(1);                                       \
          _Pragma("unroll")                                                    \
          for (int mi_ = 0; mi_ < 4; ++mi_)                                    \
              _Pragma("unroll")                                                \
              for (int ni_ = 0; ni_ < 2; ++ni_) {                              \
                  acc[Q_][mi_][ni_] = __builtin_amdgcn_mfma_f32_16x16x32_bf16( \
                      AF_[mi_][0], BF_[ni_][0], acc[Q_][mi_][ni_], 0, 0, 0);   \
                  acc[Q_][mi_][ni_] = __builtin_amdgcn_mfma_f32_16x16x32_bf16( \
                      AF_[mi_][1], BF_[ni_][1], acc[Q_][mi_][ni_], 0, 0, 0);   \
              }                                                                \
          __builtin_amdgcn_s_setprio(0); }

    #define WAITB(VM_)                                                         \
        asm volatile("s_waitcnt vmcnt(" VM_ ")" ::: "memory");                 \
        __builtin_amdgcn_s_barrier();                                          \
        asm volatile("" ::: "memory");

    // Prologue: tile 0 -> buf 0, group order [A0, B0, B1, A1] (8 loads in flight)
    STAGE_HALF(Xb, mBase,        0,             0);
    STAGE_HALF(Wb, nBase,        16384,         0);
    STAGE_HALF(Wb, nBase + 128,  16384 + 8192,  0);
    STAGE_HALF(Xb, mBase + 128,  8192,          0);

    // Main loop (kt < NT-1). Wait derivation (in-order VMEM retirement):
    //  ph0 entry queue [A0,B0,B1,A1]: need A0,B0 -> vmcnt(4); stage A0'.
    //  ph1 entry [B1,A1,A0']<=6: need B1 -> newer {A1,A0'}=4 -> vmcnt(4); stage B0'.
    //  ph2 entry [A1,A0',B0']<=6: need A1 -> newer 4 -> vmcnt(4); stage B1'.
    //  ph3: nothing needed (A1 certified at ph2 barrier) -> no wait/barrier; stage A1'.
    for (int kt = 0; kt < NT - 1; ++kt) {
        const int cur   = kt & 1;
        const int abase = cur * 32768;
        const int bbase = abase + 16384;
        const int ebase = (cur ^ 1) * 32768;
        const int kn    = (kt + 1) * BK;

        bf16x8 a0[4][2], a1[4][2], b0[2][2], b1[2][2];

        // ph0: q00 = A0 x B0
        WAITB("4");
        STAGE_HALF(Xb, mBase, ebase, kn);                       // A0'
        READ_A(a0, abase);
        READ_B(b0, bbase);
        MFMA_Q(0, a0, b0);

        // ph1: q01 = A0 x B1   (A0 carried in registers)
        WAITB("4");
        STAGE_HALF(Wb, nBase, ebase + 16384, kn);               // B0'
        READ_B(b1, bbase + 8192);
        MFMA_Q(1, a0, b1);

        // ph2: q11 = A1 x B1   (B1 carried)
        WAITB("4");
        STAGE_HALF(Wb, nBase + 128, ebase + 16384 + 8192, kn);  // B1'
        READ_A(a1, abase + 8192);
        MFMA_Q(3, a1, b1);

        // ph3: q10 = A1 x B0   (both carried; no wait, no barrier)
        STAGE_HALF(Xb, mBase + 128, ebase + 8192, kn);          // A1'
        MFMA_Q(2, a1, b0);
    }

    // Tail iter kt = NT-1: no staging -> reduced counts (4,2,0).
    {
        const int abase = ((NT - 1) & 1) * 32768;
        const int bbase = abase + 16384;
        bf16x8 a0[4][2], a1[4][2], b0[2][2], b1[2][2];

        WAITB("4");                       // A0,B0 landed
        READ_A(a0, abase);
        READ_B(b0, bbase);
        MFMA_Q(0, a0, b0);

        WAITB("2");                       // B1 landed
        READ_B(b1, bbase + 8192);
        MFMA_Q(1, a0, b1);

        WAITB("0");                       // A1 landed
        READ_A(a1, abase + 8192);
        MFMA_Q(3, a1, b1);

        MFMA_Q(2, a1, b0);
    }

    #undef WAITB
    #undef MFMA_Q
    #undef READ_B
    #undef READ_A
    #undef STAGE_HALF

    // Epilogue: out = acc * sx[row] * sw[col] + bias[col]; NT stores.
    // C/D layout: col = lane&15, row = rl*4 + reg (m89/m91).
    #pragma unroll
    for (int q = 0; q < 4; ++q) {
        const int mh = q >> 1, nh = q & 1;
        #pragma unroll
        for (int mi = 0; mi < 4; ++mi) {
            const int rowb = mBase + mh * 128 + qr * 64 + mi * 16 + rl * 4;
            #pragma unroll
            for (int ni = 0; ni < 2; ++ni) {
                const int col = nBase + nh * 128 + wcol * 32 + ni * 16 + cl;
                const float swv = SW[col];
                const float bv  = BIAS[col];
                #pragma unroll
                for (int rr = 0; rr < 4; ++rr) {
                    const int row = rowb + rr;
                    float v = acc[q][mi][ni][rr] * SX[row] * swv + bv;
                    v = fminf(fmaxf(v, -1.0e5f), 1.0e5f);   // diagnostic sentinel
                    __builtin_nontemporal_store(v, OUT + (size_t)row * N_DIM + col);
                }
            }
        }
    }
}

// ---------------- fallback (R7/R8-proven): inline-convert reg-staged 128^2 ----------------
#define FBM 128
#define FBK 64
__global__ __launch_bounds__(256) void linear_flh_gemm_f32in(
    const float* __restrict__ X, const float* __restrict__ SX,
    const float* __restrict__ W, const float* __restrict__ SW,
    const float* __restrict__ BIAS, float* __restrict__ OUT)
{
    __shared__ alignas(16) unsigned short smA[FBM * FBK];
    __shared__ alignas(16) unsigned short smB[FBM * FBK];
    const int t = threadIdx.x;
    const int lane = t & 63, wave = t >> 6;
    const int wr = wave >> 1, wc = wave & 1;
    int bid = blockIdx.x;
    bid = (bid & 7) * ((M_DIM / FBM) * (N_DIM / FBM) / 8) + (bid >> 3);
    const int mBase = (bid / (N_DIM / FBM)) * FBM;
    const int nBase = (bid % (N_DIM / FBM)) * FBM;
    const int cl = lane & 15, rl = lane >> 4;
    f32x4 acc[4][4];
    #pragma unroll
    for (int i = 0; i < 4; ++i)
        #pragma unroll
        for (int j = 0; j < 4; ++j) acc[i][j] = (f32x4){0.f, 0.f, 0.f, 0.f};
    for (int kt = 0; kt < K_DIM / FBK; ++kt) {
        const int kBase = kt * FBK;
        f32x4 ra[8], rb[8];
        #pragma unroll
        for (int cc = 0; cc < 8; ++cc) {
            const int e = cc * 1024 + t * 4;
            const int r = e >> 6, c = e & 63;
            ra[cc] = *(const f32x4*)(X + (size_t)(mBase + r) * K_DIM + kBase + c);
            rb[cc] = *(const f32x4*)(W + (size_t)(nBase + r) * K_DIM + kBase + c);
        }
        __syncthreads();
        #pragma unroll
        for (int cc = 0; cc < 8; ++cc) {
            const int e = cc * 1024 + t * 4;
            u16x4 pa, pb;
            #pragma unroll
            for (int q = 0; q < 4; ++q) { pa[q] = f2bf(ra[cc][q]); pb[q] = f2bf(rb[cc][q]); }
            *(u16x4*)(smA + e) = pa;
            *(u16x4*)(smB + e) = pb;
        }
        __syncthreads();
        #pragma unroll
        for (int kk = 0; kk < FBK / 32; ++kk) {
            bf16x8 afr[4], bfr[4];
            #pragma unroll
            for (int i = 0; i < 4; ++i) {
                afr[i] = *(const bf16x8*)(smA + (wr * 64 + i * 16 + cl) * FBK + kk * 32 + rl * 8);
                bfr[i] = *(const bf16x8*)(smB + (wc * 64 + i * 16 + cl) * FBK + kk * 32 + rl * 8);
            }
            #pragma unroll
            for (int i = 0; i < 4; ++i)
                #pragma unroll
                for (int j = 0; j < 4; ++j)
                    acc[i][j] = __builtin_amdgcn_mfma_f32_16x16x32_bf16(
                        afr[i], bfr[j], acc[i][j], 0, 0, 0);
        }
    }
    #pragma unroll
    for (int j = 0; j < 4; ++j) {
        const int gn = nBase + wc * 64 + j * 16 + cl;
        const float swv = SW[gn], bv = BIAS[gn];
        #pragma unroll
        for (int i = 0; i < 4; ++i) {
            const int gmb = mBase + wr * 64 + i * 16 + rl * 4;
            #pragma unroll
            for (int r = 0; r < 4; ++r) {
                float v = acc[i][j][r] * SX[gmb + r] * swv + bv;
                v = fminf(fmaxf(v, -1.0e5f), 1.0e5f);
                OUT[(size_t)(gmb + r) * N_DIM + gn] = v;
            }
        }
    }
}

extern "C" void kernel_launch(void* const* d_in, const int* in_sizes, int n_in,
                              void* d_out, int out_size, void* d_ws, size_t ws_size,
                              hipStream_t stream) {
    const void* pX = d_in[0]; const void* pSX = d_in[1]; const void* pW = d_in[2];
    const void* pSW = d_in[3]; const void* pBS = d_in[4];
    for (int i = 0; i < n_in; ++i) {
        if (in_sizes[i] == M_DIM * K_DIM)      pX  = d_in[i];
        else if (in_sizes[i] == M_DIM)         pSX = d_in[i];
        else if (in_sizes[i] == N_DIM * K_DIM) pW  = d_in[i];
    }
    {
        int first = -1, second = -1;
        for (int i = 0; i < n_in; ++i)
            if (in_sizes[i] == N_DIM) { if (first < 0) first = i; else if (second < 0) second = i; }
        if (first >= 0)  pSW = d_in[first];
        if (second >= 0) pBS = d_in[second];
    }

    if (ws_size >= WS_NEEDED) {
        unsigned short* Xb = (unsigned short*)d_ws;
        unsigned short* Wb = Xb + X_ELEMS;
        convert_f32_to_bf16<<<2048, 256, 0, stream>>>((const float*)pX, Xb, X_ELEMS);
        convert_f32_to_bf16<<<2048, 256, 0, stream>>>((const float*)pW, Wb, W_ELEMS);
        linear_flh_gemm_256<<<dim3(NWG), 512, 0, stream>>>(
            Xb, Wb, (const float*)pSX, (const float*)pSW, (const float*)pBS,
            (float*)d_out);
    } else {
        dim3 grid((M_DIM / FBM) * (N_DIM / FBM));
        linear_flh_gemm_f32in<<<grid, 256, 0, stream>>>(
            (const float*)pX, (const float*)pSX, (const float*)pW,
            (const float*)pSW, (const float*)pBS, (float*)d_out);
    }
}

// Round 14
// 698.851 us; speedup vs baseline: 1.2094x; 1.0472x over previous
//
#include <hip/hip_runtime.h>
#include <hip/hip_bf16.h>

// LinearFLH: out[m,n] = sx[m]*sw[n]*(x[m,:].w[n,:]) + bias[n]
// M=8192, N=11008, K=4096. All harness buffers FLOAT32 (fp16 ref -> "else
// float" rule). Pipeline: (1) f32->bf16 convert of X,W into d_ws, (2) 256x256
// BK=64 bf16 MFMA GEMM, 8 waves, 4-phase counted-vmcnt schedule (R13, 732us).
// R14 CHANGE (single): block->tile map is now a K-SYNCHRONIZED 2D CLUSTER:
//   xcd = bid&7; s = bid>>3; tm = xcd*4 + (s&3); tn = s>>2
// Each XCD's 32 concurrent CUs form a 4x8 (MxN) patch -> per K-tile they need
// 4 A-slices + 8 B-slices = 384 KB (L2-resident) instead of 1 A + 32 B
// (~1.1 MB -> L3 stream). R13 diagnosis: operand feed 7.4 TB/s from L3+HBM
// (FETCH 1.5 GB vs 150 MB ideal) caps MfmaUtil at ~49%; demand at MFMA floor
// would be 16 TB/s. This cuts L3-level demand ~5x.

#define M_DIM 8192
#define N_DIM 11008
#define K_DIM 4096
#define BM 256
#define BN 256
#define BK 64
#define NT (K_DIM / BK)                       // 64 K-tiles
#define NWG ((M_DIM / BM) * (N_DIM / BN))     // 32*43 = 1376, % 8 == 0

#define X_ELEMS (M_DIM * K_DIM)
#define W_ELEMS (N_DIM * K_DIM)
#define WS_NEEDED ((size_t)(X_ELEMS + W_ELEMS) * 2)

typedef __bf16 bf16x8 __attribute__((ext_vector_type(8)));
typedef float f32x4 __attribute__((ext_vector_type(4)));
typedef unsigned short u16x4 __attribute__((ext_vector_type(4)));
typedef unsigned short u16x8 __attribute__((ext_vector_type(8)));

typedef __attribute__((address_space(3))) void lds_void;
typedef const __attribute__((address_space(1))) void gmem_void;

// f32 -> bf16 bits, round-to-nearest-even (inputs finite)
__device__ __forceinline__ unsigned short f2bf(float f) {
    union { float f; unsigned int u; } c; c.f = f;
    unsigned int r = c.u + 0x7FFFu + ((c.u >> 16) & 1u);
    return (unsigned short)(r >> 16);
}

// ---------------- elementwise convert: f32 -> bf16 (proven R8) ----------------
__global__ __launch_bounds__(256) void convert_f32_to_bf16(
    const float* __restrict__ in, unsigned short* __restrict__ out, int n)
{
    int idx = (blockIdx.x * 256 + threadIdx.x) * 8;
    const int stride = gridDim.x * 256 * 8;
    for (; idx < n; idx += stride) {
        const f32x4 a = *(const f32x4*)(in + idx);
        const f32x4 b = *(const f32x4*)(in + idx + 4);
        u16x8 o;
        #pragma unroll
        for (int q = 0; q < 4; ++q) { o[q] = f2bf(a[q]); o[q + 4] = f2bf(b[q]); }
        *(u16x8*)(out + idx) = o;
    }
}

// ---------------- main GEMM: 256x256, 8 waves, 4-phase counted-vmcnt ----------------
// LDS: buf c at c*32768 (ushort): A [256][64] at +0 (half h at +h*8192),
// B [256][64] at +16384 (half h at +16384+h*8192).
// T2 swizzle (both sides, rule #21): lds[row][col] = global[row][col ^ ((row&7)<<3)].
__global__ __launch_bounds__(512, 2) void linear_flh_gemm_256(
    const unsigned short* __restrict__ Xb,   // [M,K] bf16 bits (ws)
    const unsigned short* __restrict__ Wb,   // [N,K] bf16 bits (ws)
    const float* __restrict__ SX,            // [M]
    const float* __restrict__ SW,            // [N]
    const float* __restrict__ BIAS,          // [N]
    float* __restrict__ OUT)                 // [M,N] f32
{
    __shared__ unsigned short lds[65536];    // 128 KiB -> 1 workgroup/CU

    const int t    = threadIdx.x;     // 0..511
    const int lane = t & 63;
    const int wid  = t >> 6;          // 0..7
    const int qr   = wid >> 2;        // 0..1: wave-row within 128x128 quadrant
    const int wcol = wid & 3;         // 0..3: wave-col within quadrant
    const int cl   = lane & 15;       // fragment row/col
    const int rl   = lane >> 4;       // 0..3: k-group

    // R14: K-synchronized 2D cluster map (bijective).
    // XCD x owns M-band [4x,4x+4); within-XCD order = N-stripes of 4 m's ->
    // 32 concurrent CUs = 4x8 patch -> 12 slices/K-tile (384 KB) in L2.
    const int bid = blockIdx.x;
    const int xcd = bid & 7;
    const int s   = bid >> 3;                 // 0..171
    const int tm  = xcd * 4 + (s & 3);        // 0..31
    const int tn  = s >> 2;                   // 0..42
    const int mBase = tm * BM;
    const int nBase = tn * BN;

    // T2 read-side: element col = (k0) ^ ((row&7)<<3); row&7 == cl&7 below.
    const int colK0 = (rl * 8) ^ ((cl & 7) << 3);
    const int colK1 = colK0 ^ 32;

    f32x4 acc[4][4][2];   // [quadrant mh*2+nh][mi][ni]
    #pragma unroll
    for (int q = 0; q < 4; ++q)
        #pragma unroll
        for (int mi = 0; mi < 4; ++mi)
            #pragma unroll
            for (int ni = 0; ni < 2; ++ni)
                acc[q][mi][ni] = (f32x4){0.f, 0.f, 0.f, 0.f};

    // Stage one 128-row HALF (A or B) = 8192 elems = 2 gload_lds(16B)/thread.
    // LDS dest linear (m104); global col pre-swizzled (rule #21).
    #define STAGE_HALF(P_, ROWB_, DSTB_, KCOL_)                                \
        { _Pragma("unroll")                                                    \
          for (int q_ = 0; q_ < 2; ++q_) {                                     \
              const int e_ = q_ * 4096 + t * 8;                                \
              const int r_ = e_ >> 6;                                          \
              const int c_ = ((t & 7) * 8) ^ ((r_ & 7) << 3);                  \
              __builtin_amdgcn_global_load_lds(                                \
                  (gmem_void*)((P_) + (size_t)((ROWB_) + r_) * K_DIM + (KCOL_) + c_),\
                  (lds_void*)(lds + (DSTB_) + e_), 16, 0, 0);                  \
          } }

    #define READ_A(DST_, HB_)                                                  \
        { _Pragma("unroll")                                                    \
          for (int mi_ = 0; mi_ < 4; ++mi_) {                                  \
              const int row_ = qr * 64 + mi_ * 16 + cl;                        \
              DST_[mi_][0] = *(const bf16x8*)(lds + (HB_) + row_ * 64 + colK0);\
              DST_[mi_][1] = *(const bf16x8*)(lds + (HB_) + row_ * 64 + colK1);\
          } }
    #define READ_B(DST_, HB_)                                                  \
        { _Pragma("unroll")                                                    \
          for (int ni_ = 0; ni_ < 2; ++ni_) {                                  \
              const int row_ = wcol * 32 + ni_ * 16 + cl;                      \
              DST_[ni_][0] = *(const bf16x8*)(lds + (HB_) + row_ * 64 + colK0);\
              DST_[ni_][1] = *(const bf16x8*)(lds + (HB_) + row_ * 64 + colK1);\
          } }

    #define MFMA_Q(Q_, AF_, BF_)                                               \
        { __builtin_amdgcn_s_setprio(1);                                       \
          _Pragma("unroll")                                                    \
          for (int mi_ = 0; mi_ < 4; ++mi_)                                    \
              _Pragma("unroll")                                                \
              for (int ni_ = 0; ni_ < 2; ++ni_) {                              \
                  acc[Q_][mi_][ni_] = __builtin_amdgcn_mfma_f32_16x16x32_bf16( \
                      AF_[mi_][0], BF_[ni_][0], acc[Q_][mi_][ni_], 0, 0, 0);   \
                  acc[Q_][mi_][ni_] = __builtin_amdgcn_mfma_f32_16x16x32_bf16( \
                      AF_[mi_][1], BF_[ni_][1], acc[Q_][mi_][ni_], 0, 0, 0);   \
              }                                                                \
          __builtin_amdgcn_s_setprio(0); }

    #define WAITB(VM_)                                                         \
        asm volatile("s_waitcnt vmcnt(" VM_ ")" ::: "memory");                 \
        __builtin_amdgcn_s_barrier();                                          \
        asm volatile("" ::: "memory");

    // Prologue: tile 0 -> buf 0, group order [A0, B0, B1, A1] (8 loads in flight)
    STAGE_HALF(Xb, mBase,        0,             0);
    STAGE_HALF(Wb, nBase,        16384,         0);
    STAGE_HALF(Wb, nBase + 128,  16384 + 8192,  0);
    STAGE_HALF(Xb, mBase + 128,  8192,          0);

    // Main loop (kt < NT-1). Wait derivation (in-order VMEM retirement):
    //  ph0 entry queue [A0,B0,B1,A1]: need A0,B0 -> vmcnt(4); stage A0'.
    //  ph1 entry [B1,A1,A0']<=6: need B1 -> newer {A1,A0'}=4 -> vmcnt(4); stage B0'.
    //  ph2 entry [A1,A0',B0']<=6: need A1 -> newer 4 -> vmcnt(4); stage B1'.
    //  ph3: nothing needed (A1 certified at ph2 barrier) -> no wait/barrier; stage A1'.
    for (int kt = 0; kt < NT - 1; ++kt) {
        const int cur   = kt & 1;
        const int abase = cur * 32768;
        const int bbase = abase + 16384;
        const int ebase = (cur ^ 1) * 32768;
        const int kn    = (kt + 1) * BK;

        bf16x8 a0[4][2], a1[4][2], b0[2][2], b1[2][2];

        // ph0: q00 = A0 x B0
        WAITB("4");
        STAGE_HALF(Xb, mBase, ebase, kn);                       // A0'
        READ_A(a0, abase);
        READ_B(b0, bbase);
        MFMA_Q(0, a0, b0);

        // ph1: q01 = A0 x B1   (A0 carried in registers)
        WAITB("4");
        STAGE_HALF(Wb, nBase, ebase + 16384, kn);               // B0'
        READ_B(b1, bbase + 8192);
        MFMA_Q(1, a0, b1);

        // ph2: q11 = A1 x B1   (B1 carried)
        WAITB("4");
        STAGE_HALF(Wb, nBase + 128, ebase + 16384 + 8192, kn);  // B1'
        READ_A(a1, abase + 8192);
        MFMA_Q(3, a1, b1);

        // ph3: q10 = A1 x B0   (both carried; no wait, no barrier)
        STAGE_HALF(Xb, mBase + 128, ebase + 8192, kn);          // A1'
        MFMA_Q(2, a1, b0);
    }

    // Tail iter kt = NT-1: no staging -> reduced counts (4,2,0).
    {
        const int abase = ((NT - 1) & 1) * 32768;
        const int bbase = abase + 16384;
        bf16x8 a0[4][2], a1[4][2], b0[2][2], b1[2][2];

        WAITB("4");                       // A0,B0 landed
        READ_A(a0, abase);
        READ_B(b0, bbase);
        MFMA_Q(0, a0, b0);

        WAITB("2");                       // B1 landed
        READ_B(b1, bbase + 8192);
        MFMA_Q(1, a0, b1);

        WAITB("0");                       // A1 landed
        READ_A(a1, abase + 8192);
        MFMA_Q(3, a1, b1);

        MFMA_Q(2, a1, b0);
    }

    #undef WAITB
    #undef MFMA_Q
    #undef READ_B
    #undef READ_A
    #undef STAGE_HALF

    // Epilogue: out = acc * sx[row] * sw[col] + bias[col]; NT stores.
    // C/D layout: col = lane&15, row = rl*4 + reg (m89/m91).
    #pragma unroll
    for (int q = 0; q < 4; ++q) {
        const int mh = q >> 1, nh = q & 1;
        #pragma unroll
        for (int mi = 0; mi < 4; ++mi) {
            const int rowb = mBase + mh * 128 + qr * 64 + mi * 16 + rl * 4;
            #pragma unroll
            for (int ni = 0; ni < 2; ++ni) {
                const int col = nBase + nh * 128 + wcol * 32 + ni * 16 + cl;
                const float swv = SW[col];
                const float bv  = BIAS[col];
                #pragma unroll
                for (int rr = 0; rr < 4; ++rr) {
                    const int row = rowb + rr;
                    float v = acc[q][mi][ni][rr] * SX[row] * swv + bv;
                    v = fminf(fmaxf(v, -1.0e5f), 1.0e5f);   // diagnostic sentinel
                    __builtin_nontemporal_store(v, OUT + (size_t)row * N_DIM + col);
                }
            }
        }
    }
}

// ---------------- fallback (R7/R8-proven): inline-convert reg-staged 128^2 ----------------
#define FBM 128
#define FBK 64
__global__ __launch_bounds__(256) void linear_flh_gemm_f32in(
    const float* __restrict__ X, const float* __restrict__ SX,
    const float* __restrict__ W, const float* __restrict__ SW,
    const float* __restrict__ BIAS, float* __restrict__ OUT)
{
    __shared__ alignas(16) unsigned short smA[FBM * FBK];
    __shared__ alignas(16) unsigned short smB[FBM * FBK];
    const int t = threadIdx.x;
    const int lane = t & 63, wave = t >> 6;
    const int wr = wave >> 1, wc = wave & 1;
    int bid = blockIdx.x;
    bid = (bid & 7) * ((M_DIM / FBM) * (N_DIM / FBM) / 8) + (bid >> 3);
    const int mBase = (bid / (N_DIM / FBM)) * FBM;
    const int nBase = (bid % (N_DIM / FBM)) * FBM;
    const int cl = lane & 15, rl = lane >> 4;
    f32x4 acc[4][4];
    #pragma unroll
    for (int i = 0; i < 4; ++i)
        #pragma unroll
        for (int j = 0; j < 4; ++j) acc[i][j] = (f32x4){0.f, 0.f, 0.f, 0.f};
    for (int kt = 0; kt < K_DIM / FBK; ++kt) {
        const int kBase = kt * FBK;
        f32x4 ra[8], rb[8];
        #pragma unroll
        for (int cc = 0; cc < 8; ++cc) {
            const int e = cc * 1024 + t * 4;
            const int r = e >> 6, c = e & 63;
            ra[cc] = *(const f32x4*)(X + (size_t)(mBase + r) * K_DIM + kBase + c);
            rb[cc] = *(const f32x4*)(W + (size_t)(nBase + r) * K_DIM + kBase + c);
        }
        __syncthreads();
        #pragma unroll
        for (int cc = 0; cc < 8; ++cc) {
            const int e = cc * 1024 + t * 4;
            u16x4 pa, pb;
            #pragma unroll
            for (int q = 0; q < 4; ++q) { pa[q] = f2bf(ra[cc][q]); pb[q] = f2bf(rb[cc][q]); }
            *(u16x4*)(smA + e) = pa;
            *(u16x4*)(smB + e) = pb;
        }
        __syncthreads();
        #pragma unroll
        for (int kk = 0; kk < FBK / 32; ++kk) {
            bf16x8 afr[4], bfr[4];
            #pragma unroll
            for (int i = 0; i < 4; ++i) {
                afr[i] = *(const bf16x8*)(smA + (wr * 64 + i * 16 + cl) * FBK + kk * 32 + rl * 8);
                bfr[i] = *(const bf16x8*)(smB + (wc * 64 + i * 16 + cl) * FBK + kk * 32 + rl * 8);
            }
            #pragma unroll
            for (int i = 0; i < 4; ++i)
                #pragma unroll
                for (int j = 0; j < 4; ++j)
                    acc[i][j] = __builtin_amdgcn_mfma_f32_16x16x32_bf16(
                        afr[i], bfr[j], acc[i][j], 0, 0, 0);
        }
    }
    #pragma unroll
    for (int j = 0; j < 4; ++j) {
        const int gn = nBase + wc * 64 + j * 16 + cl;
        const float swv = SW[gn], bv = BIAS[gn];
        #pragma unroll
        for (int i = 0; i < 4; ++i) {
            const int gmb = mBase + wr * 64 + i * 16 + rl * 4;
            #pragma unroll
            for (int r = 0; r < 4; ++r) {
                float v = acc[i][j][r] * SX[gmb + r] * swv + bv;
                v = fminf(fmaxf(v, -1.0e5f), 1.0e5f);
                OUT[(size_t)(gmb + r) * N_DIM + gn] = v;
            }
        }
    }
}

extern "C" void kernel_launch(void* const* d_in, const int* in_sizes, int n_in,
                              void* d_out, int out_size, void* d_ws, size_t ws_size,
                              hipStream_t stream) {
    const void* pX = d_in[0]; const void* pSX = d_in[1]; const void* pW = d_in[2];
    const void* pSW = d_in[3]; const void* pBS = d_in[4];
    for (int i = 0; i < n_in; ++i) {
        if (in_sizes[i] == M_DIM * K_DIM)      pX  = d_in[i];
        else if (in_sizes[i] == M_DIM)         pSX = d_in[i];
        else if (in_sizes[i] == N_DIM * K_DIM) pW  = d_in[i];
    }
    {
        int first = -1, second = -1;
        for (int i = 0; i < n_in; ++i)
            if (in_sizes[i] == N_DIM) { if (first < 0) first = i; else if (second < 0) second = i; }
        if (first >= 0)  pSW = d_in[first];
        if (second >= 0) pBS = d_in[second];
    }

    if (ws_size >= WS_NEEDED) {
        unsigned short* Xb = (unsigned short*)d_ws;
        unsigned short* Wb = Xb + X_ELEMS;
        convert_f32_to_bf16<<<2048, 256, 0, stream>>>((const float*)pX, Xb, X_ELEMS);
        convert_f32_to_bf16<<<2048, 256, 0, stream>>>((const float*)pW, Wb, W_ELEMS);
        linear_flh_gemm_256<<<dim3(NWG), 512, 0, stream>>>(
            Xb, Wb, (const float*)pSX, (const float*)pSW, (const float*)pBS,
            (float*)d_out);
    } else {
        dim3 grid((M_DIM / FBM) * (N_DIM / FBM));
        linear_flh_gemm_f32in<<<grid, 256, 0, stream>>>(
            (const float*)pX, (const float*)pSX, (const float*)pW,
            (const float*)pSW, (const float*)pBS, (float*)d_out);
    }
}